// Round 1
// baseline (386.531 us; speedup 1.0000x reference)
//
#include <hip/hip_runtime.h>
#include <math.h>

#define NB 2
#define NS 1024
#define NC 1024
#define NH 16
#define DIMP 240

constexpr float INV_SQRT3 = 0.57735026919f;
constexpr float NEGF  = -3.0e38f;   // masked logit; exp -> 0 after softmax
constexpr float MINIT = -1.0e30f;   // softmax running-max init (> NEGF so masked entries get weight 0)

// ---------------- Kernel 1: LayerNorm ----------------
__global__ __launch_bounds__(256) void ln_kernel(const float* __restrict__ s,
                                                 const float* __restrict__ lnw,
                                                 float* __restrict__ ns) {
    int row = blockIdx.x;          // 0..2047
    int tid = threadIdx.x;         // 256 threads, 4 elems each
    const float4* sp = (const float4*)(s + (size_t)row * NC);
    float4 v = sp[tid];
    float sum = v.x + v.y + v.z + v.w;
    float sq  = v.x*v.x + v.y*v.y + v.z*v.z + v.w*v.w;
    #pragma unroll
    for (int off = 32; off; off >>= 1) {
        sum += __shfl_down(sum, off);
        sq  += __shfl_down(sq, off);
    }
    __shared__ float s1[4], s2[4];
    int wave = tid >> 6;
    if ((tid & 63) == 0) { s1[wave] = sum; s2[wave] = sq; }
    __syncthreads();
    float tot   = s1[0] + s1[1] + s1[2] + s1[3];
    float totsq = s2[0] + s2[1] + s2[2] + s2[3];
    float mu  = tot * (1.0f / NC);
    float var = totsq * (1.0f / NC) - mu * mu;
    float rstd = rsqrtf(var + 1e-5f);
    float4 w = ((const float4*)lnw)[tid];
    float4 o;
    o.x = (v.x - mu) * rstd * w.x;
    o.y = (v.y - mu) * rstd * w.y;
    o.z = (v.z - mu) * rstd * w.z;
    o.w = (v.w - mu) * rstd * w.w;
    ((float4*)(ns + (size_t)row * NC))[tid] = o;
}

// ---------------- Kernel 2: projection GEMM p = ns @ w_proj^T ----------------
// 8 rows/block, 256 threads: thread (r = tid>>5, c0 = tid&31) computes cols c0+32j, j<8 (pad to 256, skip >=240)
__global__ __launch_bounds__(256) void proj_kernel(const float* __restrict__ ns,
                                                   const float* __restrict__ wp,
                                                   float* __restrict__ p) {
    int row0 = blockIdx.x * 8;
    int tid = threadIdx.x;
    int r  = tid >> 5;
    int c0 = tid & 31;
    __shared__ float A[8][64];
    float acc[8] = {0, 0, 0, 0, 0, 0, 0, 0};
    for (int kc = 0; kc < NC; kc += 64) {
        int lt = tid;
        A[lt >> 6][lt & 63] = ns[(size_t)(row0 + (lt >> 6)) * NC + kc + (lt & 63)];
        lt = tid + 256;
        A[lt >> 6][lt & 63] = ns[(size_t)(row0 + (lt >> 6)) * NC + kc + (lt & 63)];
        __syncthreads();
        #pragma unroll
        for (int kk = 0; kk < 64; kk += 4) {
            float4 a4 = *(const float4*)&A[r][kk];
            #pragma unroll
            for (int j = 0; j < 8; j++) {
                int c = c0 + 32 * j;
                if (c < DIMP) {
                    float4 w4 = *(const float4*)(wp + (size_t)c * NC + kc + kk);
                    acc[j] = fmaf(a4.x, w4.x, fmaf(a4.y, w4.y, fmaf(a4.z, w4.z, fmaf(a4.w, w4.w, acc[j]))));
                }
            }
        }
        __syncthreads();
    }
    #pragma unroll
    for (int j = 0; j < 8; j++) {
        int c = c0 + 32 * j;
        if (c < DIMP) p[(size_t)(row0 + r) * DIMP + c] = acc[j];
    }
}

// ---------------- Kernel 3: rotate + scatter to [b][h][s] float4 layouts ----------------
__global__ __launch_bounds__(256) void build_kernel(const float* __restrict__ p,
                                                    const float* __restrict__ rot,
                                                    const float* __restrict__ trans,
                                                    float4* __restrict__ qr, float4* __restrict__ kr,
                                                    float4* __restrict__ vv, float4* __restrict__ qd,
                                                    float4* __restrict__ kd) {
    int gid = blockIdx.x * 256 + threadIdx.x;   // NB*NS*80
    if (gid >= NB * NS * 80) return;
    int j  = gid % 80;
    int bs = gid / 80;
    int b  = bs >> 10;
    int si = bs & 1023;
    const float* R  = rot + (size_t)bs * 9;
    const float* pr = p + (size_t)bs * DIMP;
    int off = (j < 48) ? 3 * j : 144 + 3 * (j - 48);
    float vx = pr[off], vy = pr[off + 1], vz = pr[off + 2];
    float ox = R[0] * vx + R[1] * vy + R[2] * vz;
    float oy = R[3] * vx + R[4] * vy + R[5] * vz;
    float oz = R[6] * vx + R[7] * vy + R[8] * vz;
    if (j >= 48) {  // dist vectors get +trans
        ox += trans[(size_t)bs * 3 + 0];
        oy += trans[(size_t)bs * 3 + 1];
        oz += trans[(size_t)bs * 3 + 2];
    }
    float4 o4 = make_float4(ox, oy, oz, 0.0f);
    if (j < 16)       qr[(size_t)(b * NH + j)        * NS + si] = o4;
    else if (j < 32)  kr[(size_t)(b * NH + (j - 16)) * NS + si] = o4;
    else if (j < 48)  vv[(size_t)(b * NH + (j - 32)) * NS + si] = o4;
    else if (j < 64)  qd[(size_t)(b * NH + (j - 48)) * NS + si] = o4;
    else              kd[(size_t)(b * NH + (j - 64)) * NS + si] = o4;
}

// ---------------- Kernel 4: attention (one wave per 4 Q-rows) ----------------
__global__ __launch_bounds__(256) void attn_kernel(
    const float4* __restrict__ qr, const float4* __restrict__ kr,
    const float4* __restrict__ qd, const float4* __restrict__ kd,
    const float4* __restrict__ vv,
    const float* __restrict__ rot,
    const int* __restrict__ seq, const int* __restrict__ chain, const int* __restrict__ amask,
    const float* __restrict__ dist_scale, const float* __restrict__ rot_scale,
    float* __restrict__ small) {
    int wid  = blockIdx.x * 4 + (threadIdx.x >> 6);
    int lane = threadIdx.x & 63;
    int qg = wid & 255;          // S/4 = 256 q-groups
    int h  = (wid >> 8) & 15;
    int b  = wid >> 12;
    int base = (b * NH + h) * NS;
    int q0 = qg * 4;
    float rts = log1pf(__expf(rot_scale[h])) * INV_SQRT3;
    float dts = log1pf(__expf(dist_scale[h])) * INV_SQRT3;

    float qrx[4], qry[4], qrz[4], qdx[4], qdy[4], qdz[4];
    int sidq[4], cidq[4];
    #pragma unroll
    for (int t = 0; t < 4; t++) {
        float4 a = qr[base + q0 + t];
        float4 d = qd[base + q0 + t];
        qrx[t] = a.x; qry[t] = a.y; qrz[t] = a.z;
        qdx[t] = d.x; qdy[t] = d.y; qdz[t] = d.z;
        sidq[t] = seq[b * NS + q0 + t];
        cidq[t] = chain[b * NS + q0 + t];
    }
    float m[4], l[4], ax[4], ay[4], az[4];
    #pragma unroll
    for (int t = 0; t < 4; t++) { m[t] = MINIT; l[t] = 0; ax[t] = 0; ay[t] = 0; az[t] = 0; }

    for (int k = lane; k < NS; k += 64) {
        float4 kv = kr[base + k];
        float4 dv = kd[base + k];
        float4 vk = vv[base + k];
        int sk = seq[b * NS + k], ck = chain[b * NS + k], am = amask[b * NS + k];
        #pragma unroll
        for (int t = 0; t < 4; t++) {
            float rt = qrx[t] * kv.x + qry[t] * kv.y + qrz[t] * kv.z;
            float dx = qdx[t] - dv.x, dy = qdy[t] - dv.y, dz = qdz[t] - dv.z;
            float dist = sqrtf(dx * dx + dy * dy + dz * dz);
            float logit = (am && ck == cidq[t])
                              ? (rt * rts - dist * dts + (sk == sidq[t] ? 1.0f : 0.0f))
                              : NEGF;
            float mn = fmaxf(m[t], logit);
            float sc = __expf(m[t] - mn);
            float pw = __expf(logit - mn);
            l[t]  = l[t] * sc + pw;
            ax[t] = ax[t] * sc + pw * vk.x;
            ay[t] = ay[t] * sc + pw * vk.y;
            az[t] = az[t] * sc + pw * vk.z;
            m[t] = mn;
        }
    }
    // butterfly merge across 64 lanes
    #pragma unroll
    for (int t = 0; t < 4; t++) {
        #pragma unroll
        for (int off = 32; off; off >>= 1) {
            float m2 = __shfl_xor(m[t], off);
            float l2 = __shfl_xor(l[t], off);
            float x2 = __shfl_xor(ax[t], off);
            float y2 = __shfl_xor(ay[t], off);
            float z2 = __shfl_xor(az[t], off);
            float mn = fmaxf(m[t], m2);
            float s1 = __expf(m[t] - mn), s2 = __expf(m2 - mn);
            l[t]  = l[t] * s1 + l2 * s2;
            ax[t] = ax[t] * s1 + x2 * s2;
            ay[t] = ay[t] * s1 + y2 * s2;
            az[t] = az[t] * s1 + z2 * s2;
            m[t] = mn;
        }
    }
    if (lane == 0) {
        #pragma unroll
        for (int t = 0; t < 4; t++) {
            int q = q0 + t;
            float inv = 1.0f / l[t];
            float ox = ax[t] * inv, oy = ay[t] * inv, oz = az[t] * inv;
            const float* R = rot + (size_t)(b * NS + q) * 9;
            // out_i = sum_j R[j][i] * o_j  (R^T)
            float wx = R[0] * ox + R[3] * oy + R[6] * oz;
            float wy = R[1] * ox + R[4] * oy + R[7] * oz;
            float wz = R[2] * ox + R[5] * oy + R[8] * oz;
            if (!amask[b * NS + q]) { wx = 0; wy = 0; wz = 0; }
            float* o = small + (size_t)(b * NS + q) * 48 + h * 3;
            o[0] = wx; o[1] = wy; o[2] = wz;
        }
    }
}

// ---------------- Kernel 5: out = small @ w_out^T ----------------
__global__ __launch_bounds__(256) void outgemm_kernel(const float* __restrict__ small,
                                                      const float* __restrict__ wout,
                                                      float* __restrict__ out) {
    int c  = blockIdx.y * 256 + threadIdx.x;    // 0..1023
    int r0 = blockIdx.x * 16;
    __shared__ float sm[16][48];
    for (int i = threadIdx.x; i < 16 * 48; i += 256)
        sm[i / 48][i % 48] = small[(size_t)(r0 + i / 48) * 48 + i % 48];
    __syncthreads();
    float w[48];
    #pragma unroll
    for (int d = 0; d < 48; d += 4) {
        float4 t = *(const float4*)(wout + (size_t)c * 48 + d);
        w[d] = t.x; w[d + 1] = t.y; w[d + 2] = t.z; w[d + 3] = t.w;
    }
    #pragma unroll 4
    for (int r = 0; r < 16; r++) {
        float acc = 0.0f;
        #pragma unroll
        for (int d = 0; d < 48; d++) acc = fmaf(w[d], sm[r][d], acc);
        out[(size_t)(r0 + r) * NC + c] = acc;
    }
}

extern "C" void kernel_launch(void* const* d_in, const int* in_sizes, int n_in,
                              void* d_out, int out_size, void* d_ws, size_t ws_size,
                              hipStream_t stream) {
    const float* s     = (const float*)d_in[0];
    const float* rot   = (const float*)d_in[1];
    const float* trans = (const float*)d_in[2];
    const float* lnw   = (const float*)d_in[3];
    const float* wproj = (const float*)d_in[4];
    const float* wout  = (const float*)d_in[5];
    const float* dsc   = (const float*)d_in[6];
    const float* rsc   = (const float*)d_in[7];
    const int* amask   = (const int*)d_in[8];
    const int* seq     = (const int*)d_in[9];
    const int* chain   = (const int*)d_in[10];
    float* out = (float*)d_out;

    // workspace layout (floats): ns[2M] | p[491520] | 5x float4 bufs | small[98304]  ~= 13.4 MB
    float* ns = (float*)d_ws;
    float* p  = ns + (size_t)NB * NS * NC;
    float4* qr = (float4*)(p + (size_t)NB * NS * DIMP);
    float4* kr = qr + (size_t)NB * NH * NS;
    float4* vv = kr + (size_t)NB * NH * NS;
    float4* qd = vv + (size_t)NB * NH * NS;
    float4* kd = qd + (size_t)NB * NH * NS;
    float* small = (float*)(kd + (size_t)NB * NH * NS);

    ln_kernel<<<NB * NS, 256, 0, stream>>>(s, lnw, ns);
    proj_kernel<<<NB * NS / 8, 256, 0, stream>>>(ns, wproj, p);
    build_kernel<<<(NB * NS * 80 + 255) / 256, 256, 0, stream>>>(p, rot, trans, qr, kr, vv, qd, kd);
    attn_kernel<<<NB * NH * NS / 16, 256, 0, stream>>>(qr, kr, qd, kd, vv, rot, seq, chain, amask, dsc, rsc, small);
    outgemm_kernel<<<dim3(NB * NS / 16, 4), 256, 0, stream>>>(small, wout, out);
}

// Round 2
// 236.954 us; speedup vs baseline: 1.6312x; 1.6312x over previous
//
#include <hip/hip_runtime.h>
#include <math.h>

#define NB 2
#define NS 1024
#define NC 1024
#define NH 16
#define DIMP 240

constexpr float INV_SQRT3 = 0.57735026919f;
constexpr float NEGF  = -3.0e38f;   // masked logit; exp -> 0 after softmax
constexpr float MINIT = -1.0e30f;   // softmax running-max init (> NEGF so masked entries get weight 0)

// ---------------- Kernel 1: LayerNorm ----------------
__global__ __launch_bounds__(256) void ln_kernel(const float* __restrict__ s,
                                                 const float* __restrict__ lnw,
                                                 float* __restrict__ ns) {
    int row = blockIdx.x;          // 0..2047
    int tid = threadIdx.x;         // 256 threads, 4 elems each
    const float4* sp = (const float4*)(s + (size_t)row * NC);
    float4 v = sp[tid];
    float sum = v.x + v.y + v.z + v.w;
    float sq  = v.x*v.x + v.y*v.y + v.z*v.z + v.w*v.w;
    #pragma unroll
    for (int off = 32; off; off >>= 1) {
        sum += __shfl_down(sum, off);
        sq  += __shfl_down(sq, off);
    }
    __shared__ float s1[4], s2[4];
    int wave = tid >> 6;
    if ((tid & 63) == 0) { s1[wave] = sum; s2[wave] = sq; }
    __syncthreads();
    float tot   = s1[0] + s1[1] + s1[2] + s1[3];
    float totsq = s2[0] + s2[1] + s2[2] + s2[3];
    float mu  = tot * (1.0f / NC);
    float var = totsq * (1.0f / NC) - mu * mu;
    float rstd = rsqrtf(var + 1e-5f);
    float4 w = ((const float4*)lnw)[tid];
    float4 o;
    o.x = (v.x - mu) * rstd * w.x;
    o.y = (v.y - mu) * rstd * w.y;
    o.z = (v.z - mu) * rstd * w.z;
    o.w = (v.w - mu) * rstd * w.w;
    ((float4*)(ns + (size_t)row * NC))[tid] = o;
}

// ---------------- Kernel 1b: transpose w_proj -> Wt[k][d]  (240x1024 -> 1024x240) ----
// tiles: 64 k x 60 d, grid = 16 (k) * 4 (d) = 64 blocks
__global__ __launch_bounds__(256) void wtrans_kernel(const float* __restrict__ wp,
                                                     float* __restrict__ wt) {
    int k0 = (blockIdx.x & 15) * 64;
    int d0 = (blockIdx.x >> 4) * 60;
    __shared__ float T[64][61];
    int tid = threadIdx.x;
    #pragma unroll
    for (int i = 0; i < 15; i++) {
        int idx = i * 256 + tid;       // 60d x 64k = 3840
        int dd = idx >> 6, kk = idx & 63;
        T[kk][dd] = wp[(size_t)(d0 + dd) * NC + k0 + kk];
    }
    __syncthreads();
    #pragma unroll
    for (int i = 0; i < 15; i++) {
        int idx = i * 256 + tid;
        int kk = idx / 60, dd = idx % 60;
        wt[(size_t)(k0 + kk) * DIMP + d0 + dd] = T[kk][dd];
    }
}

// ---------------- Kernel 2: projection GEMM p = ns @ Wt, register-tiled ----------------
// block: 256 thr = 4 waves; wave owns 8 rows; lane owns 4 cols (lanes 60..63 idle).
// grid: (2048/32 rows) x (1024/128 ksplit) = 64 x 8 = 512 blocks. atomicAdd into p.
__global__ __launch_bounds__(256) void proj_kernel(const float* __restrict__ ns,
                                                   const float* __restrict__ wt,
                                                   float* __restrict__ p) {
    int tid = threadIdx.x;
    int wave = tid >> 6, lane = tid & 63;
    int row0 = blockIdx.x * 32 + wave * 8;
    int k0 = blockIdx.y * 128;
    int c0 = lane * 4;
    bool active = c0 < DIMP;
    int c0m = active ? c0 : (DIMP - 4);   // clamp idle lanes in-bounds
    float acc[8][4];
    #pragma unroll
    for (int r = 0; r < 8; r++)
        #pragma unroll
        for (int c = 0; c < 4; c++) acc[r][c] = 0.0f;

    const float* nb = ns + (size_t)row0 * NC + k0;
    const float* wb = wt + (size_t)k0 * DIMP + c0m;

    for (int kk = 0; kk < 128; kk += 4) {
        float4 w[4];
        #pragma unroll
        for (int j = 0; j < 4; j++)
            w[j] = *(const float4*)(wb + (size_t)(kk + j) * DIMP);
        #pragma unroll
        for (int r = 0; r < 8; r++) {
            float4 a = *(const float4*)(nb + (size_t)r * NC + kk);
            #pragma unroll
            for (int c = 0; c < 4; c++) {
                float* ac = &acc[r][c];
                *ac = fmaf(a.x, ((const float*)&w[0])[c], *ac);
                *ac = fmaf(a.y, ((const float*)&w[1])[c], *ac);
                *ac = fmaf(a.z, ((const float*)&w[2])[c], *ac);
                *ac = fmaf(a.w, ((const float*)&w[3])[c], *ac);
            }
        }
    }
    if (active) {
        #pragma unroll
        for (int r = 0; r < 8; r++)
            #pragma unroll
            for (int c = 0; c < 4; c++)
                atomicAdd(&p[(size_t)(row0 + r) * DIMP + c0 + c], acc[r][c]);
    }
}

// ---------------- Kernel 3: rotate + scatter to [b][h][s] float4 layouts ----------------
__global__ __launch_bounds__(256) void build_kernel(const float* __restrict__ p,
                                                    const float* __restrict__ rot,
                                                    const float* __restrict__ trans,
                                                    float4* __restrict__ qr, float4* __restrict__ kr,
                                                    float4* __restrict__ vv, float4* __restrict__ qd,
                                                    float4* __restrict__ kd) {
    int gid = blockIdx.x * 256 + threadIdx.x;   // NB*NS*80
    if (gid >= NB * NS * 80) return;
    int j  = gid % 80;
    int bs = gid / 80;
    int b  = bs >> 10;
    int si = bs & 1023;
    const float* R  = rot + (size_t)bs * 9;
    const float* pr = p + (size_t)bs * DIMP;
    int off = (j < 48) ? 3 * j : 144 + 3 * (j - 48);
    float vx = pr[off], vy = pr[off + 1], vz = pr[off + 2];
    float ox = R[0] * vx + R[1] * vy + R[2] * vz;
    float oy = R[3] * vx + R[4] * vy + R[5] * vz;
    float oz = R[6] * vx + R[7] * vy + R[8] * vz;
    if (j >= 48) {  // dist vectors get +trans
        ox += trans[(size_t)bs * 3 + 0];
        oy += trans[(size_t)bs * 3 + 1];
        oz += trans[(size_t)bs * 3 + 2];
    }
    float4 o4 = make_float4(ox, oy, oz, 0.0f);
    if (j < 16)       qr[(size_t)(b * NH + j)        * NS + si] = o4;
    else if (j < 32)  kr[(size_t)(b * NH + (j - 16)) * NS + si] = o4;
    else if (j < 48)  vv[(size_t)(b * NH + (j - 32)) * NS + si] = o4;
    else if (j < 64)  qd[(size_t)(b * NH + (j - 48)) * NS + si] = o4;
    else              kd[(size_t)(b * NH + (j - 64)) * NS + si] = o4;
}

// ---------------- Kernel 4: attention (one wave per 4 Q-rows) ----------------
__global__ __launch_bounds__(256) void attn_kernel(
    const float4* __restrict__ qr, const float4* __restrict__ kr,
    const float4* __restrict__ qd, const float4* __restrict__ kd,
    const float4* __restrict__ vv,
    const float* __restrict__ rot,
    const int* __restrict__ seq, const int* __restrict__ chain, const int* __restrict__ amask,
    const float* __restrict__ dist_scale, const float* __restrict__ rot_scale,
    float* __restrict__ small) {
    int wid  = blockIdx.x * 4 + (threadIdx.x >> 6);
    int lane = threadIdx.x & 63;
    int qg = wid & 255;          // S/4 = 256 q-groups
    int h  = (wid >> 8) & 15;
    int b  = wid >> 12;
    int base = (b * NH + h) * NS;
    int q0 = qg * 4;
    float rts = log1pf(__expf(rot_scale[h])) * INV_SQRT3;
    float dts = log1pf(__expf(dist_scale[h])) * INV_SQRT3;

    float qrx[4], qry[4], qrz[4], qdx[4], qdy[4], qdz[4];
    int sidq[4], cidq[4];
    #pragma unroll
    for (int t = 0; t < 4; t++) {
        float4 a = qr[base + q0 + t];
        float4 d = qd[base + q0 + t];
        qrx[t] = a.x; qry[t] = a.y; qrz[t] = a.z;
        qdx[t] = d.x; qdy[t] = d.y; qdz[t] = d.z;
        sidq[t] = seq[b * NS + q0 + t];
        cidq[t] = chain[b * NS + q0 + t];
    }
    float m[4], l[4], ax[4], ay[4], az[4];
    #pragma unroll
    for (int t = 0; t < 4; t++) { m[t] = MINIT; l[t] = 0; ax[t] = 0; ay[t] = 0; az[t] = 0; }

    for (int k = lane; k < NS; k += 64) {
        float4 kv = kr[base + k];
        float4 dv = kd[base + k];
        float4 vk = vv[base + k];
        int sk = seq[b * NS + k], ck = chain[b * NS + k], am = amask[b * NS + k];
        #pragma unroll
        for (int t = 0; t < 4; t++) {
            float rt = qrx[t] * kv.x + qry[t] * kv.y + qrz[t] * kv.z;
            float dx = qdx[t] - dv.x, dy = qdy[t] - dv.y, dz = qdz[t] - dv.z;
            float dist = sqrtf(dx * dx + dy * dy + dz * dz);
            float logit = (am && ck == cidq[t])
                              ? (rt * rts - dist * dts + (sk == sidq[t] ? 1.0f : 0.0f))
                              : NEGF;
            float mn = fmaxf(m[t], logit);
            float sc = __expf(m[t] - mn);
            float pw = __expf(logit - mn);
            l[t]  = l[t] * sc + pw;
            ax[t] = ax[t] * sc + pw * vk.x;
            ay[t] = ay[t] * sc + pw * vk.y;
            az[t] = az[t] * sc + pw * vk.z;
            m[t] = mn;
        }
    }
    // butterfly merge across 64 lanes
    #pragma unroll
    for (int t = 0; t < 4; t++) {
        #pragma unroll
        for (int off = 32; off; off >>= 1) {
            float m2 = __shfl_xor(m[t], off);
            float l2 = __shfl_xor(l[t], off);
            float x2 = __shfl_xor(ax[t], off);
            float y2 = __shfl_xor(ay[t], off);
            float z2 = __shfl_xor(az[t], off);
            float mn = fmaxf(m[t], m2);
            float s1 = __expf(m[t] - mn), s2 = __expf(m2 - mn);
            l[t]  = l[t] * s1 + l2 * s2;
            ax[t] = ax[t] * s1 + x2 * s2;
            ay[t] = ay[t] * s1 + y2 * s2;
            az[t] = az[t] * s1 + z2 * s2;
            m[t] = mn;
        }
    }
    if (lane == 0) {
        #pragma unroll
        for (int t = 0; t < 4; t++) {
            int q = q0 + t;
            float inv = 1.0f / l[t];
            float ox = ax[t] * inv, oy = ay[t] * inv, oz = az[t] * inv;
            const float* R = rot + (size_t)(b * NS + q) * 9;
            // out_i = sum_j R[j][i] * o_j  (R^T)
            float wx = R[0] * ox + R[3] * oy + R[6] * oz;
            float wy = R[1] * ox + R[4] * oy + R[7] * oz;
            float wz = R[2] * ox + R[5] * oy + R[8] * oz;
            if (!amask[b * NS + q]) { wx = 0; wy = 0; wz = 0; }
            float* o = small + (size_t)(b * NS + q) * 48 + h * 3;
            o[0] = wx; o[1] = wy; o[2] = wz;
        }
    }
}

// ---------------- Kernel 5: out = small @ w_out^T ----------------
__global__ __launch_bounds__(256) void outgemm_kernel(const float* __restrict__ small,
                                                      const float* __restrict__ wout,
                                                      float* __restrict__ out) {
    int c  = blockIdx.y * 256 + threadIdx.x;    // 0..1023
    int r0 = blockIdx.x * 16;
    __shared__ float sm[16][48];
    for (int i = threadIdx.x; i < 16 * 48; i += 256)
        sm[i / 48][i % 48] = small[(size_t)(r0 + i / 48) * 48 + i % 48];
    __syncthreads();
    float w[48];
    #pragma unroll
    for (int d = 0; d < 48; d += 4) {
        float4 t = *(const float4*)(wout + (size_t)c * 48 + d);
        w[d] = t.x; w[d + 1] = t.y; w[d + 2] = t.z; w[d + 3] = t.w;
    }
    #pragma unroll 4
    for (int r = 0; r < 16; r++) {
        float acc = 0.0f;
        #pragma unroll
        for (int d = 0; d < 48; d++) acc = fmaf(w[d], sm[r][d], acc);
        out[(size_t)(r0 + r) * NC + c] = acc;
    }
}

extern "C" void kernel_launch(void* const* d_in, const int* in_sizes, int n_in,
                              void* d_out, int out_size, void* d_ws, size_t ws_size,
                              hipStream_t stream) {
    const float* s     = (const float*)d_in[0];
    const float* rot   = (const float*)d_in[1];
    const float* trans = (const float*)d_in[2];
    const float* lnw   = (const float*)d_in[3];
    const float* wproj = (const float*)d_in[4];
    const float* wout  = (const float*)d_in[5];
    const float* dsc   = (const float*)d_in[6];
    const float* rsc   = (const float*)d_in[7];
    const int* amask   = (const int*)d_in[8];
    const int* seq     = (const int*)d_in[9];
    const int* chain   = (const int*)d_in[10];
    float* out = (float*)d_out;

    // workspace layout (floats): ns[2M] | p[491520] | 5x float4 bufs | small[98304]  ~= 13.4 MB
    // Wt (1024x240) overlaps the qr region: dead before build_kernel writes qr.
    float* ns = (float*)d_ws;
    float* p  = ns + (size_t)NB * NS * NC;
    float4* qr = (float4*)(p + (size_t)NB * NS * DIMP);
    float4* kr = qr + (size_t)NB * NH * NS;
    float4* vv = kr + (size_t)NB * NH * NS;
    float4* qd = vv + (size_t)NB * NH * NS;
    float4* kd = qd + (size_t)NB * NH * NS;
    float* small = (float*)(kd + (size_t)NB * NH * NS);
    float* wt = (float*)qr;

    ln_kernel<<<NB * NS, 256, 0, stream>>>(s, lnw, ns);
    wtrans_kernel<<<64, 256, 0, stream>>>(wproj, wt);
    hipMemsetAsync(p, 0, (size_t)NB * NS * DIMP * sizeof(float), stream);
    proj_kernel<<<dim3(64, 8), 256, 0, stream>>>(ns, wt, p);
    build_kernel<<<(NB * NS * 80 + 255) / 256, 256, 0, stream>>>(p, rot, trans, qr, kr, vv, qd, kd);
    attn_kernel<<<NB * NH * NS / 16, 256, 0, stream>>>(qr, kr, qd, kd, vv, rot, seq, chain, amask, dsc, rsc, small);
    outgemm_kernel<<<dim3(NB * NS / 16, 4), 256, 0, stream>>>(small, wout, out);
}

// Round 3
// 218.398 us; speedup vs baseline: 1.7698x; 1.0850x over previous
//
#include <hip/hip_runtime.h>
#include <math.h>

#define NB 2
#define NS 1024
#define NC 1024
#define NH 16
#define DIMP 240

constexpr float INV_SQRT3 = 0.57735026919f;

// ---------------- Kernel 1: LayerNorm ----------------
__global__ __launch_bounds__(256) void ln_kernel(const float* __restrict__ s,
                                                 const float* __restrict__ lnw,
                                                 float* __restrict__ ns) {
    int row = blockIdx.x;          // 0..2047
    int tid = threadIdx.x;         // 256 threads, 4 elems each
    const float4* sp = (const float4*)(s + (size_t)row * NC);
    float4 v = sp[tid];
    float sum = v.x + v.y + v.z + v.w;
    float sq  = v.x*v.x + v.y*v.y + v.z*v.z + v.w*v.w;
    #pragma unroll
    for (int off = 32; off; off >>= 1) {
        sum += __shfl_down(sum, off);
        sq  += __shfl_down(sq, off);
    }
    __shared__ float s1[4], s2[4];
    int wave = tid >> 6;
    if ((tid & 63) == 0) { s1[wave] = sum; s2[wave] = sq; }
    __syncthreads();
    float tot   = s1[0] + s1[1] + s1[2] + s1[3];
    float totsq = s2[0] + s2[1] + s2[2] + s2[3];
    float mu  = tot * (1.0f / NC);
    float var = totsq * (1.0f / NC) - mu * mu;
    float rstd = rsqrtf(var + 1e-5f);
    float4 w = ((const float4*)lnw)[tid];
    float4 o;
    o.x = (v.x - mu) * rstd * w.x;
    o.y = (v.y - mu) * rstd * w.y;
    o.z = (v.z - mu) * rstd * w.z;
    o.w = (v.w - mu) * rstd * w.w;
    ((float4*)(ns + (size_t)row * NC))[tid] = o;
}

// ---------------- Kernel 1b: transpose w_proj -> Wt[k][d]  (240x1024 -> 1024x240) ----
__global__ __launch_bounds__(256) void wtrans_kernel(const float* __restrict__ wp,
                                                     float* __restrict__ wt) {
    int k0 = (blockIdx.x & 15) * 64;
    int d0 = (blockIdx.x >> 4) * 60;
    __shared__ float T[64][61];
    int tid = threadIdx.x;
    #pragma unroll
    for (int i = 0; i < 15; i++) {
        int idx = i * 256 + tid;       // 60d x 64k = 3840
        int dd = idx >> 6, kk = idx & 63;
        T[kk][dd] = wp[(size_t)(d0 + dd) * NC + k0 + kk];
    }
    __syncthreads();
    #pragma unroll
    for (int i = 0; i < 15; i++) {
        int idx = i * 256 + tid;
        int kk = idx / 60, dd = idx % 60;
        wt[(size_t)(k0 + kk) * DIMP + d0 + dd] = T[kk][dd];
    }
}

// ---------------- Kernel 2: proj GEMM p = ns @ Wt, register-tiled + manual dbuf ----
// wave owns 8 rows x (4 cols/lane); grid 64 rowblocks x 8 ksplit; atomicAdd into p.
__global__ __launch_bounds__(256) void proj_kernel(const float* __restrict__ ns,
                                                   const float* __restrict__ wt,
                                                   float* __restrict__ p) {
    int tid = threadIdx.x;
    int wave = tid >> 6, lane = tid & 63;
    int row0 = blockIdx.x * 32 + wave * 8;
    int k0 = blockIdx.y * 128;
    int c0 = lane * 4;
    bool active = c0 < DIMP;
    int c0m = active ? c0 : (DIMP - 4);   // clamp idle lanes in-bounds
    float acc[8][4];
    #pragma unroll
    for (int r = 0; r < 8; r++)
        #pragma unroll
        for (int c = 0; c < 4; c++) acc[r][c] = 0.0f;

    const float* nb = ns + (size_t)row0 * NC + k0;
    const float* wb = wt + (size_t)k0 * DIMP + c0m;

    float4 wcur[4], acur[8];
    #pragma unroll
    for (int j = 0; j < 4; j++) wcur[j] = *(const float4*)(wb + (size_t)j * DIMP);
    #pragma unroll
    for (int r = 0; r < 8; r++) acur[r] = *(const float4*)(nb + (size_t)r * NC);

    for (int kk = 0; kk < 128; kk += 4) {
        int kn = (kk + 4 < 128) ? (kk + 4) : 0;   // last iter: dummy reload of group 0
        float4 wnxt[4], anxt[8];
        #pragma unroll
        for (int j = 0; j < 4; j++) wnxt[j] = *(const float4*)(wb + (size_t)(kn + j) * DIMP);
        #pragma unroll
        for (int r = 0; r < 8; r++) anxt[r] = *(const float4*)(nb + (size_t)r * NC + kn);
        #pragma unroll
        for (int r = 0; r < 8; r++) {
            #pragma unroll
            for (int c = 0; c < 4; c++) {
                float* ac = &acc[r][c];
                *ac = fmaf(acur[r].x, ((const float*)&wcur[0])[c], *ac);
                *ac = fmaf(acur[r].y, ((const float*)&wcur[1])[c], *ac);
                *ac = fmaf(acur[r].z, ((const float*)&wcur[2])[c], *ac);
                *ac = fmaf(acur[r].w, ((const float*)&wcur[3])[c], *ac);
            }
        }
        #pragma unroll
        for (int j = 0; j < 4; j++) wcur[j] = wnxt[j];
        #pragma unroll
        for (int r = 0; r < 8; r++) acur[r] = anxt[r];
    }
    if (active) {
        #pragma unroll
        for (int r = 0; r < 8; r++)
            #pragma unroll
            for (int c = 0; c < 4; c++)
                atomicAdd(&p[(size_t)(row0 + r) * DIMP + c0 + c], acc[r][c]);
    }
}

// ---------------- Kernel 3: rotate + scale-fold + scatter; also packs meta ----------------
// qr *= softplus(rot_scale[h])/sqrt3 ; qd,kd (incl. trans) *= softplus(dist_scale[h])/sqrt3
__global__ __launch_bounds__(256) void build_kernel(const float* __restrict__ p,
                                                    const float* __restrict__ rot,
                                                    const float* __restrict__ trans,
                                                    const float* __restrict__ dist_scale,
                                                    const float* __restrict__ rot_scale,
                                                    const int* __restrict__ seq,
                                                    const int* __restrict__ chain,
                                                    const int* __restrict__ amask,
                                                    float4* __restrict__ qr, float4* __restrict__ kr,
                                                    float4* __restrict__ vv, float4* __restrict__ qd,
                                                    float4* __restrict__ kd,
                                                    int* __restrict__ meta) {
    int gid = blockIdx.x * 256 + threadIdx.x;   // NB*NS*80
    if (gid >= NB * NS * 80) return;
    int j  = gid % 80;
    int bs = gid / 80;
    int b  = bs >> 10;
    int si = bs & 1023;
    if (j == 0)
        meta[bs] = (amask[bs] << 16) | (chain[bs] << 8) | seq[bs];
    const float* R  = rot + (size_t)bs * 9;
    const float* pr = p + (size_t)bs * DIMP;
    int off = (j < 48) ? 3 * j : 144 + 3 * (j - 48);
    float vx = pr[off], vy = pr[off + 1], vz = pr[off + 2];
    float ox = R[0] * vx + R[1] * vy + R[2] * vz;
    float oy = R[3] * vx + R[4] * vy + R[5] * vz;
    float oz = R[6] * vx + R[7] * vy + R[8] * vz;
    if (j >= 48) {  // dist vectors get +trans
        ox += trans[(size_t)bs * 3 + 0];
        oy += trans[(size_t)bs * 3 + 1];
        oz += trans[(size_t)bs * 3 + 2];
    }
    float scale = 1.0f;
    if (j < 16)                   scale = log1pf(__expf(rot_scale[j]))  * INV_SQRT3;
    else if (j >= 48)             scale = log1pf(__expf(dist_scale[(j - 48) & 15])) * INV_SQRT3;
    ox *= scale; oy *= scale; oz *= scale;
    float4 o4 = make_float4(ox, oy, oz, 0.0f);
    if (j < 16)       qr[(size_t)(b * NH + j)        * NS + si] = o4;
    else if (j < 32)  kr[(size_t)(b * NH + (j - 16)) * NS + si] = o4;
    else if (j < 48)  vv[(size_t)(b * NH + (j - 32)) * NS + si] = o4;
    else if (j < 64)  qd[(size_t)(b * NH + (j - 48)) * NS + si] = o4;
    else              kd[(size_t)(b * NH + (j - 64)) * NS + si] = o4;
}

// ---------------- Kernel 4: attention, fixed-max softmax (no online rescale) ----------------
// logit = qr.kr - |qd-kd| + seq_eq  (scales pre-folded). Bounded => exp(logit-16) directly.
__global__ __launch_bounds__(256) void attn_kernel(
    const float4* __restrict__ qr, const float4* __restrict__ kr,
    const float4* __restrict__ qd, const float4* __restrict__ kd,
    const float4* __restrict__ vv,
    const float* __restrict__ rot,
    const int* __restrict__ meta,
    float* __restrict__ small) {
    int wid  = blockIdx.x * 4 + (threadIdx.x >> 6);
    int lane = threadIdx.x & 63;
    int qg = wid & 255;          // S/4 = 256 q-groups
    int h  = (wid >> 8) & 15;
    int b  = wid >> 12;
    int base = (b * NH + h) * NS;
    int q0 = qg * 4;

    float qrx[4], qry[4], qrz[4], qdx[4], qdy[4], qdz[4];
    int vq[4], sq[4], amq[4];
    #pragma unroll
    for (int t = 0; t < 4; t++) {
        float4 a = qr[base + q0 + t];
        float4 d = qd[base + q0 + t];
        qrx[t] = a.x; qry[t] = a.y; qrz[t] = a.z;
        qdx[t] = d.x; qdy[t] = d.y; qdz[t] = d.z;
        int mq = meta[b * NS + q0 + t];
        vq[t]  = 0x100 | ((mq >> 8) & 255);   // require am_k=1 and chain_k==chain_q
        sq[t]  = mq & 255;
        amq[t] = mq >> 16;
    }
    float l[4] = {0, 0, 0, 0}, ax[4] = {0, 0, 0, 0}, ay[4] = {0, 0, 0, 0}, az[4] = {0, 0, 0, 0};

    for (int k = lane; k < NS; k += 64) {
        float4 kv = kr[base + k];
        float4 dv = kd[base + k];
        float4 vk = vv[base + k];
        int mk = meta[b * NS + k];
        int mkhi = mk >> 8, mklo = mk & 255;
        #pragma unroll
        for (int t = 0; t < 4; t++) {
            float rt = fmaf(qrx[t], kv.x, fmaf(qry[t], kv.y, qrz[t] * kv.z));
            float dx = qdx[t] - dv.x, dy = qdy[t] - dv.y, dz = qdz[t] - dv.z;
            float d2 = fmaf(dx, dx, fmaf(dy, dy, dz * dz));
            float arg = rt - sqrtf(d2) + ((mklo == sq[t]) ? -15.0f : -16.0f);
            float pw = (mkhi == vq[t]) ? __expf(arg) : 0.0f;
            l[t] += pw;
            ax[t] = fmaf(pw, vk.x, ax[t]);
            ay[t] = fmaf(pw, vk.y, ay[t]);
            az[t] = fmaf(pw, vk.z, az[t]);
        }
    }
    // plain-sum butterfly across 64 lanes
    #pragma unroll
    for (int t = 0; t < 4; t++) {
        #pragma unroll
        for (int off = 32; off; off >>= 1) {
            l[t]  += __shfl_xor(l[t], off);
            ax[t] += __shfl_xor(ax[t], off);
            ay[t] += __shfl_xor(ay[t], off);
            az[t] += __shfl_xor(az[t], off);
        }
    }
    if (lane == 0) {
        #pragma unroll
        for (int t = 0; t < 4; t++) {
            int q = q0 + t;
            float inv = 1.0f / l[t];
            float ox = ax[t] * inv, oy = ay[t] * inv, oz = az[t] * inv;
            const float* R = rot + (size_t)(b * NS + q) * 9;
            // out_i = sum_j R[j][i] * o_j  (R^T)
            float wx = R[0] * ox + R[3] * oy + R[6] * oz;
            float wy = R[1] * ox + R[4] * oy + R[7] * oz;
            float wz = R[2] * ox + R[5] * oy + R[8] * oz;
            if (!amq[t]) { wx = 0; wy = 0; wz = 0; }
            float* o = small + (size_t)(b * NS + q) * 48 + h * 3;
            o[0] = wx; o[1] = wy; o[2] = wz;
        }
    }
}

// ---------------- Kernel 5: out = small @ w_out^T ----------------
__global__ __launch_bounds__(256) void outgemm_kernel(const float* __restrict__ small,
                                                      const float* __restrict__ wout,
                                                      float* __restrict__ out) {
    int c  = blockIdx.y * 256 + threadIdx.x;    // 0..1023
    int r0 = blockIdx.x * 16;
    __shared__ float sm[16][48];
    for (int i = threadIdx.x; i < 16 * 48; i += 256)
        sm[i / 48][i % 48] = small[(size_t)(r0 + i / 48) * 48 + i % 48];
    __syncthreads();
    float w[48];
    #pragma unroll
    for (int d = 0; d < 48; d += 4) {
        float4 t = *(const float4*)(wout + (size_t)c * 48 + d);
        w[d] = t.x; w[d + 1] = t.y; w[d + 2] = t.z; w[d + 3] = t.w;
    }
    #pragma unroll 4
    for (int r = 0; r < 16; r++) {
        float acc = 0.0f;
        #pragma unroll
        for (int d = 0; d < 48; d++) acc = fmaf(w[d], sm[r][d], acc);
        out[(size_t)(r0 + r) * NC + c] = acc;
    }
}

extern "C" void kernel_launch(void* const* d_in, const int* in_sizes, int n_in,
                              void* d_out, int out_size, void* d_ws, size_t ws_size,
                              hipStream_t stream) {
    const float* s     = (const float*)d_in[0];
    const float* rot   = (const float*)d_in[1];
    const float* trans = (const float*)d_in[2];
    const float* lnw   = (const float*)d_in[3];
    const float* wproj = (const float*)d_in[4];
    const float* wout  = (const float*)d_in[5];
    const float* dsc   = (const float*)d_in[6];
    const float* rsc   = (const float*)d_in[7];
    const int* amask   = (const int*)d_in[8];
    const int* seq     = (const int*)d_in[9];
    const int* chain   = (const int*)d_in[10];
    float* out = (float*)d_out;

    // workspace (floats): ns[2M] | p[491520] | 5x float4 bufs | small[98304] | meta[2048]
    // Wt (1024x240) overlaps the qr region: dead before build_kernel writes qr.
    float* ns = (float*)d_ws;
    float* p  = ns + (size_t)NB * NS * NC;
    float4* qr = (float4*)(p + (size_t)NB * NS * DIMP);
    float4* kr = qr + (size_t)NB * NH * NS;
    float4* vv = kr + (size_t)NB * NH * NS;
    float4* qd = vv + (size_t)NB * NH * NS;
    float4* kd = qd + (size_t)NB * NH * NS;
    float* small = (float*)(kd + (size_t)NB * NH * NS);
    int* meta = (int*)(small + (size_t)NB * NS * 48);
    float* wt = (float*)qr;

    ln_kernel<<<NB * NS, 256, 0, stream>>>(s, lnw, ns);
    wtrans_kernel<<<64, 256, 0, stream>>>(wproj, wt);
    hipMemsetAsync(p, 0, (size_t)NB * NS * DIMP * sizeof(float), stream);
    proj_kernel<<<dim3(64, 8), 256, 0, stream>>>(ns, wt, p);
    build_kernel<<<(NB * NS * 80 + 255) / 256, 256, 0, stream>>>(p, rot, trans, dsc, rsc,
                                                                 seq, chain, amask,
                                                                 qr, kr, vv, qd, kd, meta);
    attn_kernel<<<NB * NH * NS / 16, 256, 0, stream>>>(qr, kr, qd, kd, vv, rot, meta, small);
    outgemm_kernel<<<dim3(NB * NS / 16, 4), 256, 0, stream>>>(small, wout, out);
}

// Round 4
// 161.315 us; speedup vs baseline: 2.3961x; 1.3539x over previous
//
#include <hip/hip_runtime.h>
#include <math.h>

#define NB 2
#define NS 1024
#define NC 1024
#define NH 16
#define DIMP 240
#define KSPLIT 8

constexpr float INV_SQRT3 = 0.57735026919f;

// ---------------- Kernel 1: LayerNorm ----------------
__global__ __launch_bounds__(256) void ln_kernel(const float* __restrict__ s,
                                                 const float* __restrict__ lnw,
                                                 float* __restrict__ ns) {
    int row = blockIdx.x;          // 0..2047
    int tid = threadIdx.x;         // 256 threads, 4 elems each
    const float4* sp = (const float4*)(s + (size_t)row * NC);
    float4 v = sp[tid];
    float sum = v.x + v.y + v.z + v.w;
    float sq  = v.x*v.x + v.y*v.y + v.z*v.z + v.w*v.w;
    #pragma unroll
    for (int off = 32; off; off >>= 1) {
        sum += __shfl_down(sum, off);
        sq  += __shfl_down(sq, off);
    }
    __shared__ float s1[4], s2[4];
    int wave = tid >> 6;
    if ((tid & 63) == 0) { s1[wave] = sum; s2[wave] = sq; }
    __syncthreads();
    float tot   = s1[0] + s1[1] + s1[2] + s1[3];
    float totsq = s2[0] + s2[1] + s2[2] + s2[3];
    float mu  = tot * (1.0f / NC);
    float var = totsq * (1.0f / NC) - mu * mu;
    float rstd = rsqrtf(var + 1e-5f);
    float4 w = ((const float4*)lnw)[tid];
    float4 o;
    o.x = (v.x - mu) * rstd * w.x;
    o.y = (v.y - mu) * rstd * w.y;
    o.z = (v.z - mu) * rstd * w.z;
    o.w = (v.w - mu) * rstd * w.w;
    ((float4*)(ns + (size_t)row * NC))[tid] = o;
}

// ---------------- Kernel 1b: transpose w_proj -> Wt[k][d]  (240x1024 -> 1024x240) ----
__global__ __launch_bounds__(256) void wtrans_kernel(const float* __restrict__ wp,
                                                     float* __restrict__ wt) {
    int k0 = (blockIdx.x & 15) * 64;
    int d0 = (blockIdx.x >> 4) * 60;
    __shared__ float T[64][61];
    int tid = threadIdx.x;
    #pragma unroll
    for (int i = 0; i < 15; i++) {
        int idx = i * 256 + tid;       // 60d x 64k = 3840
        int dd = idx >> 6, kk = idx & 63;
        T[kk][dd] = wp[(size_t)(d0 + dd) * NC + k0 + kk];
    }
    __syncthreads();
    #pragma unroll
    for (int i = 0; i < 15; i++) {
        int idx = i * 256 + tid;
        int kk = idx / 60, dd = idx % 60;
        wt[(size_t)(k0 + kk) * DIMP + d0 + dd] = T[kk][dd];
    }
}

// ---------------- Kernel 2: proj GEMM, LDS-staged A + pipelined W ----------------
// grid (64 rowblocks, 8 ksplit), 256 thr. Output: partial slab pp[ky] (plain stores)
// or atomicAdd into p when use_atomic (ws too small for partials).
__global__ __launch_bounds__(256) void proj_kernel(const float* __restrict__ ns,
                                                   const float* __restrict__ wt,
                                                   float* __restrict__ pp,
                                                   int use_atomic) {
    int tid = threadIdx.x;
    int wave = tid >> 6, lane = tid & 63;
    int row0 = blockIdx.x * 32;
    int ky = blockIdx.y;
    int k0 = ky * 128;

    __shared__ float A[32][128];
    #pragma unroll
    for (int i = 0; i < 4; i++) {
        int idx = tid + i * 256;          // float4 index, 1024 total
        int r = idx >> 5, c4 = idx & 31;
        *(float4*)&A[r][c4 * 4] = *(const float4*)(ns + (size_t)(row0 + r) * NC + k0 + c4 * 4);
    }
    __syncthreads();

    int wr0 = wave * 8;
    int c0 = lane * 4;
    bool active = c0 < DIMP;
    int c0m = active ? c0 : (DIMP - 4);
    const float* wb = wt + (size_t)k0 * DIMP + c0m;

    float acc[8][4];
    #pragma unroll
    for (int r = 0; r < 8; r++)
        #pragma unroll
        for (int c = 0; c < 4; c++) acc[r][c] = 0.0f;

    float4 wa[4], wx[4];
    #pragma unroll
    for (int j = 0; j < 4; j++) wa[j] = *(const float4*)(wb + (size_t)j * DIMP);

    for (int g = 0; g < 32; g += 2) {
        // prefetch group g+1 into wx
        #pragma unroll
        for (int j = 0; j < 4; j++)
            wx[j] = *(const float4*)(wb + (size_t)((g + 1) * 4 + j) * DIMP);
        #pragma unroll
        for (int r = 0; r < 8; r++) {
            float4 a4 = *(const float4*)&A[wr0 + r][g * 4];
            #pragma unroll
            for (int c = 0; c < 4; c++) {
                float* ac = &acc[r][c];
                *ac = fmaf(a4.x, ((const float*)&wa[0])[c], *ac);
                *ac = fmaf(a4.y, ((const float*)&wa[1])[c], *ac);
                *ac = fmaf(a4.z, ((const float*)&wa[2])[c], *ac);
                *ac = fmaf(a4.w, ((const float*)&wa[3])[c], *ac);
            }
        }
        // prefetch group g+2 into wa (clamp at end)
        int kn2 = (g + 2 < 32) ? (g + 2) * 4 : 0;
        #pragma unroll
        for (int j = 0; j < 4; j++)
            wa[j] = *(const float4*)(wb + (size_t)(kn2 + j) * DIMP);
        #pragma unroll
        for (int r = 0; r < 8; r++) {
            float4 a4 = *(const float4*)&A[wr0 + r][(g + 1) * 4];
            #pragma unroll
            for (int c = 0; c < 4; c++) {
                float* ac = &acc[r][c];
                *ac = fmaf(a4.x, ((const float*)&wx[0])[c], *ac);
                *ac = fmaf(a4.y, ((const float*)&wx[1])[c], *ac);
                *ac = fmaf(a4.z, ((const float*)&wx[2])[c], *ac);
                *ac = fmaf(a4.w, ((const float*)&wx[3])[c], *ac);
            }
        }
    }
    if (active) {
        if (use_atomic) {
            #pragma unroll
            for (int r = 0; r < 8; r++)
                #pragma unroll
                for (int c = 0; c < 4; c++)
                    atomicAdd(&pp[(size_t)(row0 + wr0 + r) * DIMP + c0 + c], acc[r][c]);
        } else {
            float* dst = pp + (size_t)ky * (NB * NS * DIMP);
            #pragma unroll
            for (int r = 0; r < 8; r++)
                *(float4*)(dst + (size_t)(row0 + wr0 + r) * DIMP + c0) =
                    make_float4(acc[r][0], acc[r][1], acc[r][2], acc[r][3]);
        }
    }
}

// ---------------- Kernel 2b: reduce partials, in-place on pp[0] ----------------
__global__ __launch_bounds__(256) void reduce_kernel(float4* __restrict__ pp) {
    int i = blockIdx.x * 256 + threadIdx.x;   // float4 idx, 2048*240/4 = 122880
    const int stride = NB * NS * DIMP / 4;
    float4 s = pp[i];
    #pragma unroll
    for (int ky = 1; ky < KSPLIT; ky++) {
        float4 t = pp[i + (size_t)ky * stride];
        s.x += t.x; s.y += t.y; s.z += t.z; s.w += t.w;
    }
    pp[i] = s;
}

// ---------------- Kernel 3: rotate + scale-fold + scatter; also packs meta ----------------
__global__ __launch_bounds__(256) void build_kernel(const float* __restrict__ p,
                                                    const float* __restrict__ rot,
                                                    const float* __restrict__ trans,
                                                    const float* __restrict__ dist_scale,
                                                    const float* __restrict__ rot_scale,
                                                    const int* __restrict__ seq,
                                                    const int* __restrict__ chain,
                                                    const int* __restrict__ amask,
                                                    float4* __restrict__ qr, float4* __restrict__ kr,
                                                    float4* __restrict__ vv, float4* __restrict__ qd,
                                                    float4* __restrict__ kd,
                                                    int* __restrict__ meta) {
    int gid = blockIdx.x * 256 + threadIdx.x;   // NB*NS*80
    if (gid >= NB * NS * 80) return;
    int j  = gid % 80;
    int bs = gid / 80;
    int b  = bs >> 10;
    int si = bs & 1023;
    if (j == 0)
        meta[bs] = (amask[bs] << 16) | (chain[bs] << 8) | seq[bs];
    const float* R  = rot + (size_t)bs * 9;
    const float* pr = p + (size_t)bs * DIMP;
    int off = (j < 48) ? 3 * j : 144 + 3 * (j - 48);
    float vx = pr[off], vy = pr[off + 1], vz = pr[off + 2];
    float ox = R[0] * vx + R[1] * vy + R[2] * vz;
    float oy = R[3] * vx + R[4] * vy + R[5] * vz;
    float oz = R[6] * vx + R[7] * vy + R[8] * vz;
    if (j >= 48) {  // dist vectors get +trans
        ox += trans[(size_t)bs * 3 + 0];
        oy += trans[(size_t)bs * 3 + 1];
        oz += trans[(size_t)bs * 3 + 2];
    }
    float scale = 1.0f;
    if (j < 16)                   scale = log1pf(__expf(rot_scale[j]))  * INV_SQRT3;
    else if (j >= 48)             scale = log1pf(__expf(dist_scale[(j - 48) & 15])) * INV_SQRT3;
    ox *= scale; oy *= scale; oz *= scale;
    float4 o4 = make_float4(ox, oy, oz, 0.0f);
    if (j < 16)       qr[(size_t)(b * NH + j)        * NS + si] = o4;
    else if (j < 32)  kr[(size_t)(b * NH + (j - 16)) * NS + si] = o4;
    else if (j < 48)  vv[(size_t)(b * NH + (j - 32)) * NS + si] = o4;
    else if (j < 64)  qd[(size_t)(b * NH + (j - 48)) * NS + si] = o4;
    else              kd[(size_t)(b * NH + (j - 64)) * NS + si] = o4;
}

// ---------------- Kernel 4: attention, fixed-max softmax (no online rescale) ----------------
__global__ __launch_bounds__(256) void attn_kernel(
    const float4* __restrict__ qr, const float4* __restrict__ kr,
    const float4* __restrict__ qd, const float4* __restrict__ kd,
    const float4* __restrict__ vv,
    const float* __restrict__ rot,
    const int* __restrict__ meta,
    float* __restrict__ small) {
    int wid  = blockIdx.x * 4 + (threadIdx.x >> 6);
    int lane = threadIdx.x & 63;
    int qg = wid & 255;          // S/4 = 256 q-groups
    int h  = (wid >> 8) & 15;
    int b  = wid >> 12;
    int base = (b * NH + h) * NS;
    int q0 = qg * 4;

    float qrx[4], qry[4], qrz[4], qdx[4], qdy[4], qdz[4];
    int vq[4], sq[4], amq[4];
    #pragma unroll
    for (int t = 0; t < 4; t++) {
        float4 a = qr[base + q0 + t];
        float4 d = qd[base + q0 + t];
        qrx[t] = a.x; qry[t] = a.y; qrz[t] = a.z;
        qdx[t] = d.x; qdy[t] = d.y; qdz[t] = d.z;
        int mq = meta[b * NS + q0 + t];
        vq[t]  = 0x100 | ((mq >> 8) & 255);   // require am_k=1 and chain_k==chain_q
        sq[t]  = mq & 255;
        amq[t] = mq >> 16;
    }
    float l[4] = {0, 0, 0, 0}, ax[4] = {0, 0, 0, 0}, ay[4] = {0, 0, 0, 0}, az[4] = {0, 0, 0, 0};

    for (int k = lane; k < NS; k += 64) {
        float4 kv = kr[base + k];
        float4 dv = kd[base + k];
        float4 vk = vv[base + k];
        int mk = meta[b * NS + k];
        int mkhi = mk >> 8, mklo = mk & 255;
        #pragma unroll
        for (int t = 0; t < 4; t++) {
            float rt = fmaf(qrx[t], kv.x, fmaf(qry[t], kv.y, qrz[t] * kv.z));
            float dx = qdx[t] - dv.x, dy = qdy[t] - dv.y, dz = qdz[t] - dv.z;
            float d2 = fmaf(dx, dx, fmaf(dy, dy, dz * dz));
            float arg = rt - sqrtf(d2) + ((mklo == sq[t]) ? -15.0f : -16.0f);
            float pw = (mkhi == vq[t]) ? __expf(arg) : 0.0f;
            l[t] += pw;
            ax[t] = fmaf(pw, vk.x, ax[t]);
            ay[t] = fmaf(pw, vk.y, ay[t]);
            az[t] = fmaf(pw, vk.z, az[t]);
        }
    }
    // plain-sum butterfly across 64 lanes
    #pragma unroll
    for (int t = 0; t < 4; t++) {
        #pragma unroll
        for (int off = 32; off; off >>= 1) {
            l[t]  += __shfl_xor(l[t], off);
            ax[t] += __shfl_xor(ax[t], off);
            ay[t] += __shfl_xor(ay[t], off);
            az[t] += __shfl_xor(az[t], off);
        }
    }
    if (lane == 0) {
        #pragma unroll
        for (int t = 0; t < 4; t++) {
            int q = q0 + t;
            float inv = 1.0f / l[t];
            float ox = ax[t] * inv, oy = ay[t] * inv, oz = az[t] * inv;
            const float* R = rot + (size_t)(b * NS + q) * 9;
            // out_i = sum_j R[j][i] * o_j  (R^T)
            float wx = R[0] * ox + R[3] * oy + R[6] * oz;
            float wy = R[1] * ox + R[4] * oy + R[7] * oz;
            float wz = R[2] * ox + R[5] * oy + R[8] * oz;
            if (!amq[t]) { wx = 0; wy = 0; wz = 0; }
            float* o = small + (size_t)(b * NS + q) * 48 + h * 3;
            o[0] = wx; o[1] = wy; o[2] = wz;
        }
    }
}

// ---------------- Kernel 5: out = small @ w_out^T ----------------
__global__ __launch_bounds__(256) void outgemm_kernel(const float* __restrict__ small,
                                                      const float* __restrict__ wout,
                                                      float* __restrict__ out) {
    int c  = blockIdx.y * 256 + threadIdx.x;    // 0..1023
    int r0 = blockIdx.x * 16;
    __shared__ float sm[16][48];
    for (int i = threadIdx.x; i < 16 * 48; i += 256)
        sm[i / 48][i % 48] = small[(size_t)(r0 + i / 48) * 48 + i % 48];
    __syncthreads();
    float w[48];
    #pragma unroll
    for (int d = 0; d < 48; d += 4) {
        float4 t = *(const float4*)(wout + (size_t)c * 48 + d);
        w[d] = t.x; w[d + 1] = t.y; w[d + 2] = t.z; w[d + 3] = t.w;
    }
    #pragma unroll 4
    for (int r = 0; r < 16; r++) {
        float acc = 0.0f;
        #pragma unroll
        for (int d = 0; d < 48; d++) acc = fmaf(w[d], sm[r][d], acc);
        out[(size_t)(r0 + r) * NC + c] = acc;
    }
}

extern "C" void kernel_launch(void* const* d_in, const int* in_sizes, int n_in,
                              void* d_out, int out_size, void* d_ws, size_t ws_size,
                              hipStream_t stream) {
    const float* s     = (const float*)d_in[0];
    const float* rot   = (const float*)d_in[1];
    const float* trans = (const float*)d_in[2];
    const float* lnw   = (const float*)d_in[3];
    const float* wproj = (const float*)d_in[4];
    const float* wout  = (const float*)d_in[5];
    const float* dsc   = (const float*)d_in[6];
    const float* rsc   = (const float*)d_in[7];
    const int* amask   = (const int*)d_in[8];
    const int* seq     = (const int*)d_in[9];
    const int* chain   = (const int*)d_in[10];
    float* out = (float*)d_out;

    // ws layout (floats): ns[2097152] | qr,kr,vv,qd,kd (5x131072) | small[98304] |
    //                     meta[2048 ints] | pp[KSPLIT x 491520]  (p aliases pp[0])
    // wt (983 KB) overlaps qr+kr: dead before build_kernel writes them.
    float* ns = (float*)d_ws;
    float4* qr = (float4*)(ns + (size_t)NB * NS * NC);
    float4* kr = qr + (size_t)NB * NH * NS;
    float4* vv = kr + (size_t)NB * NH * NS;
    float4* qd = vv + (size_t)NB * NH * NS;
    float4* kd = qd + (size_t)NB * NH * NS;
    float* small = (float*)(kd + (size_t)NB * NH * NS);
    int* meta = (int*)(small + (size_t)NB * NS * 48);
    float* pp = (float*)(meta + NB * NS);
    float* p  = pp;                 // reduce folds partials into pp[0]
    float* wt = (float*)qr;

    size_t need = ((char*)(pp + (size_t)KSPLIT * NB * NS * DIMP)) - (char*)d_ws;
    int use_atomic = (ws_size < need) ? 1 : 0;

    ln_kernel<<<NB * NS, 256, 0, stream>>>(s, lnw, ns);
    wtrans_kernel<<<64, 256, 0, stream>>>(wproj, wt);
    if (use_atomic) {
        hipMemsetAsync(p, 0, (size_t)NB * NS * DIMP * sizeof(float), stream);
        proj_kernel<<<dim3(64, KSPLIT), 256, 0, stream>>>(ns, wt, p, 1);
    } else {
        proj_kernel<<<dim3(64, KSPLIT), 256, 0, stream>>>(ns, wt, pp, 0);
        reduce_kernel<<<NB * NS * DIMP / 4 / 256, 256, 0, stream>>>((float4*)pp);
    }
    build_kernel<<<(NB * NS * 80 + 255) / 256, 256, 0, stream>>>(p, rot, trans, dsc, rsc,
                                                                 seq, chain, amask,
                                                                 qr, kr, vv, qd, kd, meta);
    attn_kernel<<<NB * NH * NS / 16, 256, 0, stream>>>(qr, kr, qd, kd, vv, rot, meta, small);
    outgemm_kernel<<<dim3(NB * NS / 16, 4), 256, 0, stream>>>(small, wout, out);
}

// Round 5
// 156.093 us; speedup vs baseline: 2.4763x; 1.0335x over previous
//
#include <hip/hip_runtime.h>
#include <math.h>

#define NB 2
#define NS 1024
#define NC 1024
#define NH 16
#define DIMP 240
#define KSPLIT 16

constexpr float INV_SQRT3 = 0.57735026919f;

// ---------------- Kernel 1: LayerNorm + w_proj transpose (block-split merge) ----------
// blocks 0..2047: LN row. blocks 2048..2111: transpose tile of w_proj -> Wt[k][d].
__global__ __launch_bounds__(256) void pre_kernel(const float* __restrict__ s,
                                                  const float* __restrict__ lnw,
                                                  float* __restrict__ ns,
                                                  const float* __restrict__ wp,
                                                  float* __restrict__ wt) {
    __shared__ float sh[64 * 61];
    int tid = threadIdx.x;
    if (blockIdx.x < NB * NS) {
        int row = blockIdx.x;
        const float4* sp = (const float4*)(s + (size_t)row * NC);
        float4 v = sp[tid];
        float sum = v.x + v.y + v.z + v.w;
        float sq  = v.x*v.x + v.y*v.y + v.z*v.z + v.w*v.w;
        #pragma unroll
        for (int off = 32; off; off >>= 1) {
            sum += __shfl_down(sum, off);
            sq  += __shfl_down(sq, off);
        }
        float* s1 = sh; float* s2 = sh + 4;
        int wave = tid >> 6;
        if ((tid & 63) == 0) { s1[wave] = sum; s2[wave] = sq; }
        __syncthreads();
        float tot   = s1[0] + s1[1] + s1[2] + s1[3];
        float totsq = s2[0] + s2[1] + s2[2] + s2[3];
        float mu  = tot * (1.0f / NC);
        float var = totsq * (1.0f / NC) - mu * mu;
        float rstd = rsqrtf(var + 1e-5f);
        float4 w = ((const float4*)lnw)[tid];
        float4 o;
        o.x = (v.x - mu) * rstd * w.x;
        o.y = (v.y - mu) * rstd * w.y;
        o.z = (v.z - mu) * rstd * w.z;
        o.w = (v.w - mu) * rstd * w.w;
        ((float4*)(ns + (size_t)row * NC))[tid] = o;
    } else {
        int bx = blockIdx.x - NB * NS;
        int k0 = (bx & 15) * 64;
        int d0 = (bx >> 4) * 60;
        float (*T)[61] = (float (*)[61])sh;
        #pragma unroll
        for (int i = 0; i < 15; i++) {
            int idx = i * 256 + tid;       // 60d x 64k = 3840
            int dd = idx >> 6, kk = idx & 63;
            T[kk][dd] = wp[(size_t)(d0 + dd) * NC + k0 + kk];
        }
        __syncthreads();
        #pragma unroll
        for (int i = 0; i < 15; i++) {
            int idx = i * 256 + tid;
            int kk = idx / 60, dd = idx % 60;
            wt[(size_t)(k0 + kk) * DIMP + d0 + dd] = T[kk][dd];
        }
    }
}

// ---------------- Kernel 2: proj GEMM, LDS-staged A + pipelined W, KSPLIT=16 --------
// grid (64 rowblocks, 16 ksplit), 256 thr; 64-k slab. Partial slab per ky (plain
// stores) or atomicAdd into pp[0] when use_atomic.
__global__ __launch_bounds__(256) void proj_kernel(const float* __restrict__ ns,
                                                   const float* __restrict__ wt,
                                                   float* __restrict__ pp,
                                                   int use_atomic) {
    int tid = threadIdx.x;
    int wave = tid >> 6, lane = tid & 63;
    int row0 = blockIdx.x * 32;
    int ky = blockIdx.y;
    int k0 = ky * 64;

    __shared__ float A[32][64];
    #pragma unroll
    for (int i = 0; i < 2; i++) {
        int idx = tid + i * 256;          // float4 index, 512 total
        int r = idx >> 4, c4 = idx & 15;
        *(float4*)&A[r][c4 * 4] = *(const float4*)(ns + (size_t)(row0 + r) * NC + k0 + c4 * 4);
    }
    __syncthreads();

    int wr0 = wave * 8;
    int c0 = lane * 4;
    bool active = c0 < DIMP;
    int c0m = active ? c0 : (DIMP - 4);
    const float* wb = wt + (size_t)k0 * DIMP + c0m;

    float acc[8][4];
    #pragma unroll
    for (int r = 0; r < 8; r++)
        #pragma unroll
        for (int c = 0; c < 4; c++) acc[r][c] = 0.0f;

    float4 wa[4], wx[4];
    #pragma unroll
    for (int j = 0; j < 4; j++) wa[j] = *(const float4*)(wb + (size_t)j * DIMP);

    for (int g = 0; g < 16; g += 2) {
        #pragma unroll
        for (int j = 0; j < 4; j++)
            wx[j] = *(const float4*)(wb + (size_t)((g + 1) * 4 + j) * DIMP);
        #pragma unroll
        for (int r = 0; r < 8; r++) {
            float4 a4 = *(const float4*)&A[wr0 + r][g * 4];
            #pragma unroll
            for (int c = 0; c < 4; c++) {
                float* ac = &acc[r][c];
                *ac = fmaf(a4.x, ((const float*)&wa[0])[c], *ac);
                *ac = fmaf(a4.y, ((const float*)&wa[1])[c], *ac);
                *ac = fmaf(a4.z, ((const float*)&wa[2])[c], *ac);
                *ac = fmaf(a4.w, ((const float*)&wa[3])[c], *ac);
            }
        }
        int kn2 = (g + 2 < 16) ? (g + 2) * 4 : 0;
        #pragma unroll
        for (int j = 0; j < 4; j++)
            wa[j] = *(const float4*)(wb + (size_t)(kn2 + j) * DIMP);
        #pragma unroll
        for (int r = 0; r < 8; r++) {
            float4 a4 = *(const float4*)&A[wr0 + r][(g + 1) * 4];
            #pragma unroll
            for (int c = 0; c < 4; c++) {
                float* ac = &acc[r][c];
                *ac = fmaf(a4.x, ((const float*)&wx[0])[c], *ac);
                *ac = fmaf(a4.y, ((const float*)&wx[1])[c], *ac);
                *ac = fmaf(a4.z, ((const float*)&wx[2])[c], *ac);
                *ac = fmaf(a4.w, ((const float*)&wx[3])[c], *ac);
            }
        }
    }
    if (active) {
        if (use_atomic) {
            #pragma unroll
            for (int r = 0; r < 8; r++)
                #pragma unroll
                for (int c = 0; c < 4; c++)
                    atomicAdd(&pp[(size_t)(row0 + wr0 + r) * DIMP + c0 + c], acc[r][c]);
        } else {
            float* dst = pp + (size_t)ky * (NB * NS * DIMP);
            #pragma unroll
            for (int r = 0; r < 8; r++)
                *(float4*)(dst + (size_t)(row0 + wr0 + r) * DIMP + c0) =
                    make_float4(acc[r][0], acc[r][1], acc[r][2], acc[r][3]);
        }
    }
}

// ---------------- Kernel 3: inline partial-sum + rotate + scale-fold + pack ----------
// kpack record per (b,h,k), 3 float4s: f0=(kr.xyz, ck) f1=(kd.xyz, sk) f2=(vv.xyz, 0)
// ck = chain + 1000*(1-am); qrb=(qr.xyz,0); qdb=(qd.xyz,0). Scales pre-folded.
__global__ __launch_bounds__(256) void build_kernel(const float* __restrict__ pp, int nred,
                                                    const float* __restrict__ rot,
                                                    const float* __restrict__ trans,
                                                    const float* __restrict__ dist_scale,
                                                    const float* __restrict__ rot_scale,
                                                    const int* __restrict__ seq,
                                                    const int* __restrict__ chain,
                                                    const int* __restrict__ amask,
                                                    float4* __restrict__ qrb,
                                                    float4* __restrict__ qdb,
                                                    float4* __restrict__ kp) {
    int gid = blockIdx.x * 256 + threadIdx.x;   // NB*NS*80
    if (gid >= NB * NS * 80) return;
    int j  = gid % 80;
    int bs = gid / 80;
    int b  = bs >> 10;
    int si = bs & 1023;
    int off = (j < 48) ? 3 * j : 144 + 3 * (j - 48);
    float vx = 0.0f, vy = 0.0f, vz = 0.0f;
    for (int ky = 0; ky < nred; ky++) {
        const float* pr = pp + (size_t)ky * (NB * NS * DIMP) + (size_t)bs * DIMP + off;
        vx += pr[0]; vy += pr[1]; vz += pr[2];
    }
    const float* R = rot + (size_t)bs * 9;
    float ox = R[0] * vx + R[1] * vy + R[2] * vz;
    float oy = R[3] * vx + R[4] * vy + R[5] * vz;
    float oz = R[6] * vx + R[7] * vy + R[8] * vz;
    if (j >= 48) {
        ox += trans[(size_t)bs * 3 + 0];
        oy += trans[(size_t)bs * 3 + 1];
        oz += trans[(size_t)bs * 3 + 2];
    }
    if (j < 16) {
        float sc = log1pf(__expf(rot_scale[j])) * INV_SQRT3;
        qrb[(size_t)(b * NH + j) * NS + si] = make_float4(ox * sc, oy * sc, oz * sc, 0.0f);
    } else if (j < 32) {
        int h = j - 16;
        float ck = (float)chain[bs] + 1000.0f * (float)(1 - amask[bs]);
        kp[((size_t)(b * NH + h) * NS + si) * 3 + 0] = make_float4(ox, oy, oz, ck);
    } else if (j < 48) {
        int h = j - 32;
        kp[((size_t)(b * NH + h) * NS + si) * 3 + 2] = make_float4(ox, oy, oz, 0.0f);
    } else if (j < 64) {
        int h = j - 48;
        float sc = log1pf(__expf(dist_scale[h])) * INV_SQRT3;
        qdb[(size_t)(b * NH + h) * NS + si] = make_float4(ox * sc, oy * sc, oz * sc, 0.0f);
    } else {
        int h = j - 64;
        float sc = log1pf(__expf(dist_scale[h])) * INV_SQRT3;
        kp[((size_t)(b * NH + h) * NS + si) * 3 + 1] =
            make_float4(ox * sc, oy * sc, oz * sc, (float)seq[bs]);
    }
}

// ---------------- Kernel 4: attention, packed K stream, arithmetic masking ----------
__global__ __launch_bounds__(256) void attn_kernel(
    const float4* __restrict__ qrb, const float4* __restrict__ qdb,
    const float4* __restrict__ kp,
    const float* __restrict__ rot,
    float* __restrict__ small) {
    int wid  = blockIdx.x * 4 + (threadIdx.x >> 6);
    int lane = threadIdx.x & 63;
    int qg = wid & 255;          // S/4 = 256 q-groups
    int h  = (wid >> 8) & 15;
    int b  = wid >> 12;
    int base = (b * NH + h) * NS;
    int q0 = qg * 4;
    const float4* kb = kp + (size_t)base * 3;

    float qrx[4], qry[4], qrz[4], qdx[4], qdy[4], qdz[4], cq[4], sq[4];
    #pragma unroll
    for (int t = 0; t < 4; t++) {
        float4 a = qrb[base + q0 + t];
        float4 d = qdb[base + q0 + t];
        qrx[t] = a.x; qry[t] = a.y; qrz[t] = a.z;
        qdx[t] = d.x; qdy[t] = d.y; qdz[t] = d.z;
        cq[t] = kb[(size_t)(q0 + t) * 3 + 0].w;
        sq[t] = kb[(size_t)(q0 + t) * 3 + 1].w;
    }
    float l[4] = {0, 0, 0, 0}, ax[4] = {0, 0, 0, 0}, ay[4] = {0, 0, 0, 0}, az[4] = {0, 0, 0, 0};

    for (int k = lane; k < NS; k += 64) {
        float4 f0 = kb[(size_t)k * 3 + 0];
        float4 f1 = kb[(size_t)k * 3 + 1];
        float4 f2 = kb[(size_t)k * 3 + 2];
        #pragma unroll
        for (int t = 0; t < 4; t++) {
            float rt = fmaf(qrx[t], f0.x, fmaf(qry[t], f0.y, qrz[t] * f0.z));
            float dx = qdx[t] - f1.x, dy = qdy[t] - f1.y, dz = qdz[t] - f1.z;
            float d2 = fmaf(dx, dx, fmaf(dy, dy, dz * dz));
            float dist = sqrtf(d2);
            float dc = f0.w - cq[t];
            float arg = fmaf(-100.0f, fabsf(dc), rt - dist) +
                        ((f1.w == sq[t]) ? -15.0f : -16.0f);
            float pw = __expf(arg);   // masked (|dc|>=1) underflows to 0
            l[t] += pw;
            ax[t] = fmaf(pw, f2.x, ax[t]);
            ay[t] = fmaf(pw, f2.y, ay[t]);
            az[t] = fmaf(pw, f2.z, az[t]);
        }
    }
    // plain-sum butterfly across 64 lanes
    #pragma unroll
    for (int t = 0; t < 4; t++) {
        #pragma unroll
        for (int off = 32; off; off >>= 1) {
            l[t]  += __shfl_xor(l[t], off);
            ax[t] += __shfl_xor(ax[t], off);
            ay[t] += __shfl_xor(ay[t], off);
            az[t] += __shfl_xor(az[t], off);
        }
    }
    if (lane == 0) {
        #pragma unroll
        for (int t = 0; t < 4; t++) {
            int q = q0 + t;
            float inv = 1.0f / l[t];
            float ox = ax[t] * inv, oy = ay[t] * inv, oz = az[t] * inv;
            const float* R = rot + (size_t)(b * NS + q) * 9;
            // out_i = sum_j R[j][i] * o_j  (R^T)
            float wx = R[0] * ox + R[3] * oy + R[6] * oz;
            float wy = R[1] * ox + R[4] * oy + R[7] * oz;
            float wz = R[2] * ox + R[5] * oy + R[8] * oz;
            if (cq[t] >= 500.0f) { wx = 0; wy = 0; wz = 0; }  // am_q == 0
            float* o = small + (size_t)(b * NS + q) * 48 + h * 3;
            o[0] = wx; o[1] = wy; o[2] = wz;
        }
    }
}

// ---------------- Kernel 5: out = small @ w_out^T ----------------
__global__ __launch_bounds__(256) void outgemm_kernel(const float* __restrict__ small,
                                                      const float* __restrict__ wout,
                                                      float* __restrict__ out) {
    int c  = blockIdx.y * 256 + threadIdx.x;    // 0..1023
    int r0 = blockIdx.x * 16;
    __shared__ float sm[16][48];
    for (int i = threadIdx.x; i < 16 * 48; i += 256)
        sm[i / 48][i % 48] = small[(size_t)(r0 + i / 48) * 48 + i % 48];
    __syncthreads();
    float w[48];
    #pragma unroll
    for (int d = 0; d < 48; d += 4) {
        float4 t = *(const float4*)(wout + (size_t)c * 48 + d);
        w[d] = t.x; w[d + 1] = t.y; w[d + 2] = t.z; w[d + 3] = t.w;
    }
    #pragma unroll 4
    for (int r = 0; r < 16; r++) {
        float acc = 0.0f;
        #pragma unroll
        for (int d = 0; d < 48; d++) acc = fmaf(w[d], sm[r][d], acc);
        out[(size_t)(r0 + r) * NC + c] = acc;
    }
}

extern "C" void kernel_launch(void* const* d_in, const int* in_sizes, int n_in,
                              void* d_out, int out_size, void* d_ws, size_t ws_size,
                              hipStream_t stream) {
    const float* s     = (const float*)d_in[0];
    const float* rot   = (const float*)d_in[1];
    const float* trans = (const float*)d_in[2];
    const float* lnw   = (const float*)d_in[3];
    const float* wproj = (const float*)d_in[4];
    const float* wout  = (const float*)d_in[5];
    const float* dsc   = (const float*)d_in[6];
    const float* rsc   = (const float*)d_in[7];
    const int* amask   = (const int*)d_in[8];
    const int* seq     = (const int*)d_in[9];
    const int* chain   = (const int*)d_in[10];
    float* out = (float*)d_out;

    // ws layout (floats): ns[2097152] | qrb[131072] | qdb[131072] | kp[393216] |
    //                     small[98304] | pp[KSPLIT x 491520]   ~= 43 MB
    // wt (983 KB) overlays qrb+qdb: dead before build_kernel writes them.
    float* ns = (float*)d_ws;
    float4* qrb = (float4*)(ns + (size_t)NB * NS * NC);
    float4* qdb = qrb + (size_t)NB * NH * NS;
    float4* kpk = qdb + (size_t)NB * NH * NS;
    float* small = (float*)(kpk + (size_t)3 * NB * NH * NS);
    float* pp = small + (size_t)NB * NS * 48;
    float* wt = (float*)qrb;

    size_t need = ((char*)(pp + (size_t)KSPLIT * NB * NS * DIMP)) - (char*)d_ws;
    int use_atomic = (ws_size < need) ? 1 : 0;

    pre_kernel<<<NB * NS + 64, 256, 0, stream>>>(s, lnw, ns, wproj, wt);
    if (use_atomic) {
        hipMemsetAsync(pp, 0, (size_t)NB * NS * DIMP * sizeof(float), stream);
        proj_kernel<<<dim3(64, KSPLIT), 256, 0, stream>>>(ns, wt, pp, 1);
        build_kernel<<<(NB * NS * 80 + 255) / 256, 256, 0, stream>>>(pp, 1, rot, trans, dsc, rsc,
                                                                     seq, chain, amask, qrb, qdb, kpk);
    } else {
        proj_kernel<<<dim3(64, KSPLIT), 256, 0, stream>>>(ns, wt, pp, 0);
        build_kernel<<<(NB * NS * 80 + 255) / 256, 256, 0, stream>>>(pp, KSPLIT, rot, trans, dsc, rsc,
                                                                     seq, chain, amask, qrb, qdb, kpk);
    }
    attn_kernel<<<NB * NH * NS / 16, 256, 0, stream>>>(qrb, qdb, kpk, rot, small);
    outgemm_kernel<<<dim3(NB * NS / 16, 4), 256, 0, stream>>>(small, wout, out);
}